// Round 16
// baseline (1187.887 us; speedup 1.0000x reference)
//
#include <hip/hip_runtime.h>

#define N_NODES 50000
#define N_EDGES 600000
#define DIM 128
#define HID 256
#define MR 32            // rows per tile; edge blocks run 2 tiles sequentially

typedef float  f32x4  __attribute__((ext_vector_type(4), aligned(16), may_alias));
typedef float  f32x2  __attribute__((ext_vector_type(2), aligned(8),  may_alias));
typedef __bf16 bf16x8 __attribute__((ext_vector_type(8), aligned(16), may_alias));
typedef int    i32x4  __attribute__((ext_vector_type(4), aligned(16), may_alias));

static __device__ inline f32x4 mfma16x16x32(bf16x8 a, bf16x8 b, f32x4 c) {
    return __builtin_amdgcn_mfma_f32_16x16x32_bf16(a, b, c, 0, 0, 0);
}

static __device__ inline bf16x8 cvt2_bf16(f32x4 a, f32x4 b) {
    bf16x8 o;
    o[0] = (__bf16)a[0]; o[1] = (__bf16)a[1]; o[2] = (__bf16)a[2]; o[3] = (__bf16)a[3];
    o[4] = (__bf16)b[0]; o[5] = (__bf16)b[1]; o[6] = (__bf16)b[2]; o[7] = (__bf16)b[3];
    return o;
}

// ---------------------------------------------------------------------------
// Fused prep: nbf table (3125 blocks) | weight pack (112) | hist (2344)
// ---------------------------------------------------------------------------
static __device__ inline void pack_one(const float* __restrict__ W,
                                       __bf16* __restrict__ out,
                                       int idx, int Ncols) {
    int lane = idx & 63;
    int tc = idx >> 6;
    int nC = Ncols >> 4;
    int c = tc % nC;
    int t = tc / nC;
    int col = (c << 4) + (lane & 15);
    int k0 = (t << 5) + ((lane >> 4) << 3);
    bf16x8 v;
#pragma unroll
    for (int j = 0; j < 8; ++j) v[j] = (__bf16)W[(k0 + j) * Ncols + col];
    *((bf16x8*)out + idx) = v;
}

__global__ void prep_kernel(const float* __restrict__ node, __bf16* __restrict__ nbf,
                            const float* __restrict__ eW1, const float* __restrict__ eW2,
                            const float* __restrict__ nW1, const float* __restrict__ nW2,
                            __bf16* __restrict__ peW1, __bf16* __restrict__ peW2,
                            __bf16* __restrict__ pnW1, __bf16* __restrict__ pnW2,
                            const int* __restrict__ eidx, int* __restrict__ counts) {
    int b = blockIdx.x;
    if (b < 3125) {                       // nbf: fp32 -> bf16 node table
        int idx = b * 256 + threadIdx.x;
        if (idx >= N_NODES * 16) return;
        int row = idx >> 4, c = idx & 15;
        const float* p = node + (size_t)row * DIM + (c << 3);
        f32x4 a = ((const f32x4*)p)[0], bb = ((const f32x4*)p)[1];
        *(bf16x8*)(nbf + (size_t)row * DIM + (c << 3)) = cvt2_bf16(a, bb);
    } else if (b < 3237) {                // pack all four weights
        int idx = (b - 3125) * 256 + threadIdx.x;
        if (idx < 12288)       pack_one(eW1, peW1, idx, 256);
        else if (idx < 16384)  pack_one(eW2, peW2, idx - 12288, 128);
        else if (idx < 24576)  pack_one(nW1, pnW1, idx - 16384, 256);
        else                   pack_one(nW2, pnW2, idx - 24576, 128);
    } else {                              // hist
        int e = (b - 3237) * 256 + threadIdx.x;
        if (e < N_EDGES) {
            int r = eidx[N_EDGES + e];
            r = (r < 0) ? 0 : (r >= N_NODES ? N_NODES - 1 : r);
            atomicAdd(&counts[r], 1);
        }
    }
}

// ---------------------------------------------------------------------------
// CSR build: scan + scatter
// ---------------------------------------------------------------------------
__global__ __launch_bounds__(1024) void scan_kernel(const int* __restrict__ counts,
                                                    int* __restrict__ offsets,
                                                    int* __restrict__ cursor) {
    __shared__ int part[1024];
    const int t = threadIdx.x;
    const int CH = (N_NODES + 1023) / 1024;   // 49
    const int base = t * CH;
    int s = 0;
#pragma unroll 1
    for (int i = 0; i < CH; ++i) {
        int idx = base + i;
        if (idx < N_NODES) s += counts[idx];
    }
    part[t] = s;
    __syncthreads();
    for (int d = 1; d < 1024; d <<= 1) {
        int x = (t >= d) ? part[t - d] : 0;
        __syncthreads();
        part[t] += x;
        __syncthreads();
    }
    int run = part[t] - s;
#pragma unroll 1
    for (int i = 0; i < CH; ++i) {
        int idx = base + i;
        if (idx < N_NODES) {
            offsets[idx] = run;
            cursor[idx]  = run;
            run += counts[idx];
        }
    }
    if (t == 1023) offsets[N_NODES] = run;
}

__global__ void scatter_kernel(const int* __restrict__ eidx,
                               int* __restrict__ cursor, int* __restrict__ eids) {
    int e = blockIdx.x * 256 + threadIdx.x;
    if (e < N_EDGES) {
        int r = eidx[N_EDGES + e];
        r = (r < 0) ? 0 : (r >= N_NODES ? N_NODES - 1 : r);
        int pos = atomicAdd(&cursor[r], 1);
        eids[pos] = e;
    }
}

// ---------------------------------------------------------------------------
// Aggregation: one wave per node (round-15)
// ---------------------------------------------------------------------------
__global__ __launch_bounds__(256) void agg_kernel(
    const float* __restrict__ out_edges,
    const int* __restrict__ offsets, const int* __restrict__ eids,
    float* __restrict__ agg) {
    const int tid = threadIdx.x;
    const int n = blockIdx.x * 4 + (tid >> 6);
    const int lane = tid & 63;
    const int es = lane >> 4;       // edge slot 0..3
    const int cg = lane & 15;       // col group: 8 floats (32B)
    float a[8];
#pragma unroll
    for (int j = 0; j < 8; ++j) a[j] = 0.f;
    int st = offsets[n], en = offsets[n + 1];
#pragma unroll 1
    for (int i = st + es; i < en; i += 4) {
        int e = eids[i];
        const float* p = out_edges + (size_t)e * DIM + (cg << 3);
        f32x4 v0 = ((const f32x4*)p)[0], v1 = ((const f32x4*)p)[1];
        a[0] += v0[0]; a[1] += v0[1]; a[2] += v0[2]; a[3] += v0[3];
        a[4] += v1[0]; a[5] += v1[1]; a[6] += v1[2]; a[7] += v1[3];
    }
#pragma unroll
    for (int j = 0; j < 8; ++j) {
        a[j] += __shfl_xor(a[j], 16);
        a[j] += __shfl_xor(a[j], 32);
    }
    if (es == 0) {
        float* q = agg + (size_t)n * DIM + (cg << 3);
        f32x4 w0 = {a[0], a[1], a[2], a[3]};
        f32x4 w1 = {a[4], a[5], a[6], a[7]};
        ((f32x4*)q)[0] = w0;
        ((f32x4*)q)[1] = w1;
    }
}

// ---------------------------------------------------------------------------
// Fused MLP core (round-10): 4 waves, 4-way N-split, in-register LN,
// fast-math SiLU (exp2 + rcp).
// ---------------------------------------------------------------------------
template<int ASTRIDE, int T1>
__device__ inline void mlp_core(char* lds,
                                const bf16x8* __restrict__ pW1,
                                const bf16x8* __restrict__ pW2,
                                const float* __restrict__ b1,
                                const float* __restrict__ g1,
                                const float* __restrict__ be1,
                                f32x4 (&acc2)[2][2]) {
    const int tid = threadIdx.x;
    const int w = tid >> 6;
    const int lane = tid & 63;
    const int l16 = lane & 15;
    const int g = lane >> 4;
    float* stats = (float*)(lds + 32 * ASTRIDE);   // [32][8]: (sum,sq) x 4 waves

    // ---- GEMM1: [32,K1] x [K1,256], wave w owns cols [64w, 64w+64) ----
    f32x4 acc[2][4];
#pragma unroll
    for (int m = 0; m < 2; ++m)
#pragma unroll
        for (int n = 0; n < 4; ++n) acc[m][n] = (f32x4){0.f, 0.f, 0.f, 0.f};
#pragma unroll
    for (int t = 0; t < T1; ++t) {
        bf16x8 af[2];
#pragma unroll
        for (int m = 0; m < 2; ++m)
            af[m] = *(const bf16x8*)(lds + (m * 16 + l16) * ASTRIDE + t * 64 + g * 16);
        const bf16x8* bp = pW1 + ((t * 16 + 4 * w) << 6) + lane;
#pragma unroll
        for (int n = 0; n < 4; ++n) {
            bf16x8 bf = bp[n << 6];
#pragma unroll
            for (int m = 0; m < 2; ++m)
                acc[m][n] = mfma16x16x32(af[m], bf, acc[m][n]);
        }
    }

    // ---- bias + per-row stats (vectorized over r) ----
    float b1v[4];
#pragma unroll
    for (int n = 0; n < 4; ++n) b1v[n] = b1[64 * w + 16 * n + l16];
#pragma unroll
    for (int m = 0; m < 2; ++m) {
#pragma unroll
        for (int n = 0; n < 4; ++n) acc[m][n] += b1v[n];
        f32x4 s = (acc[m][0] + acc[m][1]) + (acc[m][2] + acc[m][3]);
        f32x4 q = acc[m][0] * acc[m][0];
        q = acc[m][1] * acc[m][1] + q;
        q = acc[m][2] * acc[m][2] + q;
        q = acc[m][3] * acc[m][3] + q;
#pragma unroll
        for (int st = 1; st <= 8; st <<= 1) {
#pragma unroll
            for (int r = 0; r < 4; ++r) {
                s[r] += __shfl_xor(s[r], st);
                q[r] += __shfl_xor(q[r], st);
            }
        }
        if (l16 == 0) {
#pragma unroll
            for (int r = 0; r < 4; ++r) {
                int row = m * 16 + g * 4 + r;
                *(f32x2*)(stats + row * 8 + w * 2) = (f32x2){s[r], q[r]};
            }
        }
    }
    __syncthreads();   // GEMM1 A-reads done everywhere; stats visible

    // ---- finish LN stats; apply LN + fast SiLU; write h' (over A region) ----
    f32x4 mu4[2], rs4[2];
#pragma unroll
    for (int m = 0; m < 2; ++m)
#pragma unroll
        for (int r = 0; r < 4; ++r) {
            int row = m * 16 + g * 4 + r;
            f32x4 a = *(const f32x4*)(stats + row * 8);
            f32x4 b = *(const f32x4*)(stats + row * 8 + 4);
            float S = (a[0] + a[2]) + (b[0] + b[2]);
            float Q = (a[1] + a[3]) + (b[1] + b[3]);
            float mm = S * (1.f / 256.f);
            float vv = fmaxf(Q * (1.f / 256.f) - mm * mm, 0.f);
            mu4[m][r] = mm;
            rs4[m][r] = __builtin_amdgcn_rsqf(vv + 1e-5f);
        }
    float g1v[4], bev[4];
#pragma unroll
    for (int n = 0; n < 4; ++n) {
        g1v[n] = g1[64 * w + 16 * n + l16];
        bev[n] = be1[64 * w + 16 * n + l16];
    }
#pragma unroll
    for (int m = 0; m < 2; ++m)
#pragma unroll
        for (int n = 0; n < 4; ++n) {
            f32x4 y = (acc[m][n] - mu4[m]) * rs4[m];
            y = y * g1v[n] + bev[n];
            int col = 64 * w + 16 * n + l16;
#pragma unroll
            for (int r = 0; r < 4; ++r) {
                float e = __builtin_amdgcn_exp2f(y[r] * -1.44269504f);
                float x = y[r] * __builtin_amdgcn_rcpf(1.f + e);   // SiLU
                int row = m * 16 + g * 4 + r;
                *(__bf16*)(lds + row * 528 + col * 2) = (__bf16)x;
            }
        }
    __syncthreads();   // h' complete

    // ---- GEMM2: [32,256] x [256,128], wave w owns cols [32w, 32w+32) ----
#pragma unroll
    for (int m = 0; m < 2; ++m)
#pragma unroll
        for (int n = 0; n < 2; ++n) acc2[m][n] = (f32x4){0.f, 0.f, 0.f, 0.f};
#pragma unroll
    for (int t = 0; t < 8; ++t) {
        bf16x8 af[2];
#pragma unroll
        for (int m = 0; m < 2; ++m)
            af[m] = *(const bf16x8*)(lds + (m * 16 + l16) * 528 + t * 64 + g * 16);
        const bf16x8* bp = pW2 + ((t * 8 + 2 * w) << 6) + lane;
#pragma unroll
        for (int n = 0; n < 2; ++n) {
            bf16x8 bf = bp[n << 6];
#pragma unroll
            for (int m = 0; m < 2; ++m)
                acc2[m][n] = mfma16x16x32(af[m], bf, acc2[m][n]);
        }
    }
}

// ---------------------------------------------------------------------------
// Edge kernel: 2 sequential 32-edge tiles/block (T14 async-stage: tile-1 ef
// loads issued before tile-0 compute, written to LDS after GEMM2 frees it).
// ---------------------------------------------------------------------------
__global__ __launch_bounds__(256, 5) void edge_kernel(
    const __bf16* __restrict__ nbf, const float* __restrict__ ef,
    const int* __restrict__ eidx,
    const bf16x8* __restrict__ pW1, const bf16x8* __restrict__ pW2,
    const float* __restrict__ b1, const float* __restrict__ g1,
    const float* __restrict__ be1, const float* __restrict__ b2,
    float* __restrict__ out_edges) {
    __shared__ __align__(16) char lds[MR * 784 + MR * 32];   // 26112 B (single buffer)
    const int tid = threadIdx.x;
    const int row = tid >> 3, l8 = tid & 7;
    const int eb = blockIdx.x * 64;
    const int w = tid >> 6, lane = tid & 63;
    const int l16 = lane & 15, g = lane >> 4;

    {   // stage tile 0
        int e = eb + row;
        int snd = eidx[e], rcv = eidx[N_EDGES + e];
        snd = (snd < 0) ? 0 : (snd >= N_NODES ? N_NODES - 1 : snd);
        rcv = (rcv < 0) ? 0 : (rcv >= N_NODES ? N_NODES - 1 : rcv);
        const char* ps = (const char*)(nbf + (size_t)snd * DIM) + (l8 << 5);
        const char* pr = (const char*)(nbf + (size_t)rcv * DIM) + (l8 << 5);
        char* dst = lds + row * 784 + (l8 << 5);
        *(i32x4*)dst         = *(const i32x4*)ps;
        *(i32x4*)(dst + 16)  = *(const i32x4*)(ps + 16);
        *(i32x4*)(dst + 256) = *(const i32x4*)pr;
        *(i32x4*)(dst + 272) = *(const i32x4*)(pr + 16);
        const float* pe = ef + (size_t)e * DIM + (l8 << 4);
        f32x4 a0 = ((const f32x4*)pe)[0], a1 = ((const f32x4*)pe)[1];
        f32x4 a2 = ((const f32x4*)pe)[2], a3 = ((const f32x4*)pe)[3];
        *(bf16x8*)(dst + 512) = cvt2_bf16(a0, a1);
        *(bf16x8*)(dst + 528) = cvt2_bf16(a2, a3);
    }
    __syncthreads();

    // ---- T14 issue-early: tile-1 ef loads + eidx (fly during tile-0 MLP) ----
    const int e1 = eb + 32 + row;
    const float* pe1 = ef + (size_t)e1 * DIM + (l8 << 4);
    f32x4 c0 = ((const f32x4*)pe1)[0], c1 = ((const f32x4*)pe1)[1];
    f32x4 c2 = ((const f32x4*)pe1)[2], c3 = ((const f32x4*)pe1)[3];
    int snd1 = eidx[e1], rcv1 = eidx[N_EDGES + e1];
    snd1 = (snd1 < 0) ? 0 : (snd1 >= N_NODES ? N_NODES - 1 : snd1);
    rcv1 = (rcv1 < 0) ? 0 : (rcv1 >= N_NODES ? N_NODES - 1 : rcv1);

    f32x4 acc2[2][2];
    mlp_core<784, 12>(lds, pW1, pW2, b1, g1, be1, acc2);
    __syncthreads();                 // GEMM2 h' reads done -> LDS free

    {   // write-late: stage tile 1 (nbf gathers + register-held ef)
        const char* ps = (const char*)(nbf + (size_t)snd1 * DIM) + (l8 << 5);
        const char* pr = (const char*)(nbf + (size_t)rcv1 * DIM) + (l8 << 5);
        char* dst = lds + row * 784 + (l8 << 5);
        *(i32x4*)dst         = *(const i32x4*)ps;
        *(i32x4*)(dst + 16)  = *(const i32x4*)(ps + 16);
        *(i32x4*)(dst + 256) = *(const i32x4*)pr;
        *(i32x4*)(dst + 272) = *(const i32x4*)(pr + 16);
        *(bf16x8*)(dst + 512) = cvt2_bf16(c0, c1);
        *(bf16x8*)(dst + 528) = cvt2_bf16(c2, c3);
    }
    {   // epilogue tile 0 (global only; overlaps the ds_writes above)
        float b2v[2];
#pragma unroll
        for (int n = 0; n < 2; ++n) b2v[n] = b2[32 * w + 16 * n + l16];
#pragma unroll
        for (int m = 0; m < 2; ++m)
#pragma unroll
            for (int n = 0; n < 2; ++n)
#pragma unroll
                for (int r = 0; r < 4; ++r) {
                    int e = eb + m * 16 + g * 4 + r;
                    int col = 32 * w + 16 * n + l16;
                    size_t off = (size_t)e * DIM + col;
                    out_edges[off] = acc2[m][n][r] + b2v[n] + ef[off];
                }
    }
    __syncthreads();                 // tile-1 A-tile ready

    mlp_core<784, 12>(lds, pW1, pW2, b1, g1, be1, acc2);

    {   // epilogue tile 1
        float b2v[2];
#pragma unroll
        for (int n = 0; n < 2; ++n) b2v[n] = b2[32 * w + 16 * n + l16];
#pragma unroll
        for (int m = 0; m < 2; ++m)
#pragma unroll
            for (int n = 0; n < 2; ++n)
#pragma unroll
                for (int r = 0; r < 4; ++r) {
                    int e = eb + 32 + m * 16 + g * 4 + r;
                    int col = 32 * w + 16 * n + l16;
                    size_t off = (size_t)e * DIM + col;
                    out_edges[off] = acc2[m][n][r] + b2v[n] + ef[off];
                }
    }
}

// ---------------------------------------------------------------------------
// Node kernel: 32 nodes/block; streaming stage [nbf | agg] -> MLP. No gather.
// ---------------------------------------------------------------------------
__global__ __launch_bounds__(256, 5) void node_kernel(
    const float* __restrict__ node, const __bf16* __restrict__ nbf,
    const float* __restrict__ agg,
    const bf16x8* __restrict__ pW1, const bf16x8* __restrict__ pW2,
    const float* __restrict__ b1, const float* __restrict__ g1,
    const float* __restrict__ be1, const float* __restrict__ b2,
    float* __restrict__ out_nodes) {
    __shared__ __align__(16) char lds[MR * 528 + MR * 32];   // 17920 B
    const int tid = threadIdx.x;
    const int nb = blockIdx.x * MR;

    {   // stage node_input = [nbf[n] | agg[n] f32->bf16]
        int row = tid >> 3, l8 = tid & 7;
        int n = nb + row;
        int nc = (n > N_NODES - 1) ? N_NODES - 1 : n;
        const char* pn = (const char*)(nbf + (size_t)nc * DIM) + (l8 << 5);
        char* dst = lds + row * 528 + (l8 << 5);
        *(i32x4*)dst        = *(const i32x4*)pn;
        *(i32x4*)(dst + 16) = *(const i32x4*)(pn + 16);
        const float* ap = agg + (size_t)nc * DIM + (l8 << 4);
        f32x4 a0 = ((const f32x4*)ap)[0], a1 = ((const f32x4*)ap)[1];
        f32x4 a2 = ((const f32x4*)ap)[2], a3 = ((const f32x4*)ap)[3];
        int cbase = 16 + (l8 << 1);
        *(bf16x8*)(lds + row * 528 + (cbase << 4)) = cvt2_bf16(a0, a1);
        *(bf16x8*)(lds + row * 528 + ((cbase + 1) << 4)) = cvt2_bf16(a2, a3);
    }
    __syncthreads();

    f32x4 acc2[2][2];
    mlp_core<528, 8>(lds, pW1, pW2, b1, g1, be1, acc2);

    {   // epilogue: out = node + (h' @ W2 + b2), guarded
        const int w = tid >> 6, lane = tid & 63;
        const int l16 = lane & 15, g = lane >> 4;
        float b2v[2];
#pragma unroll
        for (int n = 0; n < 2; ++n) b2v[n] = b2[32 * w + 16 * n + l16];
#pragma unroll
        for (int m = 0; m < 2; ++m)
#pragma unroll
            for (int n = 0; n < 2; ++n)
#pragma unroll
                for (int r = 0; r < 4; ++r) {
                    int nd = nb + m * 16 + g * 4 + r;
                    if (nd < N_NODES) {
                        int col = 32 * w + 16 * n + l16;
                        size_t off = (size_t)nd * DIM + col;
                        out_nodes[off] = acc2[m][n][r] + b2v[n] + node[off];
                    }
                }
    }
}

// ---------------------------------------------------------------------------
extern "C" void kernel_launch(void* const* d_in, const int* in_sizes, int n_in,
                              void* d_out, int out_size, void* d_ws, size_t ws_size,
                              hipStream_t stream) {
    const float* node  = (const float*)d_in[0];
    const float* ef    = (const float*)d_in[1];
    const int*   eidx  = (const int*)d_in[2];
    const float* eW1   = (const float*)d_in[3];
    const float* eb1   = (const float*)d_in[4];
    const float* eg1   = (const float*)d_in[5];
    const float* ebt1  = (const float*)d_in[6];
    const float* eW2   = (const float*)d_in[7];
    const float* eb2   = (const float*)d_in[8];
    const float* nW1   = (const float*)d_in[9];
    const float* nb1   = (const float*)d_in[10];
    const float* ng1   = (const float*)d_in[11];
    const float* nbt1  = (const float*)d_in[12];
    const float* nW2   = (const float*)d_in[13];
    const float* nb2   = (const float*)d_in[14];

    char* ws = (char*)d_ws;
    int* counts  = (int*)ws;
    int* offsets = counts + 50016;
    int* cursor  = offsets + 50016;
    int* eids    = cursor + 50016;
    char* abase = (char*)(eids + 600064);
    float* agg = (float*)(((uintptr_t)abase + 255) & ~(uintptr_t)255);     // 25.6 MB
    __bf16* nbf = (__bf16*)(agg + (size_t)N_NODES * DIM);                  // 12.8 MB
    __bf16* peW1 = nbf + (size_t)N_NODES * DIM;
    __bf16* peW2 = peW1 + 384 * 256;
    __bf16* pnW1 = peW2 + 256 * 128;
    __bf16* pnW2 = pnW1 + 256 * 256;

    hipMemsetAsync(counts, 0, 50000 * sizeof(int), stream);
    prep_kernel<<<3125 + 112 + 2344, 256, 0, stream>>>(
        node, nbf, eW1, eW2, nW1, nW2, peW1, peW2, pnW1, pnW2, eidx, counts);
    scan_kernel<<<1, 1024, 0, stream>>>(counts, offsets, cursor);
    scatter_kernel<<<(N_EDGES + 255) / 256, 256, 0, stream>>>(eidx, cursor, eids);

    float* out_nodes = (float*)d_out;
    float* out_edges = out_nodes + (size_t)N_NODES * DIM;

    edge_kernel<<<N_EDGES / 64, 256, 0, stream>>>(
        nbf, ef, eidx, (const bf16x8*)peW1, (const bf16x8*)peW2,
        eb1, eg1, ebt1, eb2, out_edges);
    agg_kernel<<<N_NODES / 4, 256, 0, stream>>>(out_edges, offsets, eids, agg);
    node_kernel<<<(N_NODES + MR - 1) / MR, 256, 0, stream>>>(
        node, nbf, agg, (const bf16x8*)pnW1, (const bf16x8*)pnW2,
        nb1, ng1, nbt1, nb2, out_nodes);
}

// Round 17
// 618.034 us; speedup vs baseline: 1.9220x; 1.9220x over previous
//
#include <hip/hip_runtime.h>

#define N_NODES 50000
#define N_EDGES 600000
#define DIM 128
#define HID 256
#define MR 32            // rows (edges/nodes) per block

typedef float  f32x4  __attribute__((ext_vector_type(4), aligned(16), may_alias));
typedef float  f32x2  __attribute__((ext_vector_type(2), aligned(8),  may_alias));
typedef __bf16 bf16x8 __attribute__((ext_vector_type(8), aligned(16), may_alias));
typedef int    i32x4  __attribute__((ext_vector_type(4), aligned(16), may_alias));

static __device__ inline f32x4 mfma16x16x32(bf16x8 a, bf16x8 b, f32x4 c) {
    return __builtin_amdgcn_mfma_f32_16x16x32_bf16(a, b, c, 0, 0, 0);
}

static __device__ inline bf16x8 cvt2_bf16(f32x4 a, f32x4 b) {
    bf16x8 o;
    o[0] = (__bf16)a[0]; o[1] = (__bf16)a[1]; o[2] = (__bf16)a[2]; o[3] = (__bf16)a[3];
    o[4] = (__bf16)b[0]; o[5] = (__bf16)b[1]; o[6] = (__bf16)b[2]; o[7] = (__bf16)b[3];
    return o;
}

// ---------------------------------------------------------------------------
// node features fp32 -> bf16 table (one-time, 12.8 MB)
// ---------------------------------------------------------------------------
__global__ void nbf_kernel(const float* __restrict__ node, __bf16* __restrict__ nbf) {
    int idx = blockIdx.x * 256 + threadIdx.x;     // 50000*16 chunks
    if (idx >= N_NODES * 16) return;
    int row = idx >> 4, c = idx & 15;
    const float* p = node + (size_t)row * DIM + (c << 3);
    f32x4 a = ((const f32x4*)p)[0], b = ((const f32x4*)p)[1];
    *(bf16x8*)(nbf + (size_t)row * DIM + (c << 3)) = cvt2_bf16(a, b);
}

// ---------------------------------------------------------------------------
// Weight pre-pack (all four weights in one launch)
// ---------------------------------------------------------------------------
static __device__ inline void pack_one(const float* __restrict__ W,
                                       __bf16* __restrict__ out,
                                       int idx, int Ncols) {
    int lane = idx & 63;
    int tc = idx >> 6;
    int nC = Ncols >> 4;
    int c = tc % nC;
    int t = tc / nC;
    int col = (c << 4) + (lane & 15);
    int k0 = (t << 5) + ((lane >> 4) << 3);
    bf16x8 v;
#pragma unroll
    for (int j = 0; j < 8; ++j) v[j] = (__bf16)W[(k0 + j) * Ncols + col];
    *((bf16x8*)out + idx) = v;
}

__global__ void pack_all_kernel(const float* __restrict__ eW1, const float* __restrict__ eW2,
                                const float* __restrict__ nW1, const float* __restrict__ nW2,
                                __bf16* __restrict__ peW1, __bf16* __restrict__ peW2,
                                __bf16* __restrict__ pnW1, __bf16* __restrict__ pnW2) {
    int idx = blockIdx.x * 256 + threadIdx.x;     // 28672 total
    if (idx < 12288)       pack_one(eW1, peW1, idx, 256);
    else if (idx < 16384)  pack_one(eW2, peW2, idx - 12288, 128);
    else if (idx < 24576)  pack_one(nW1, pnW1, idx - 16384, 256);
    else                   pack_one(nW2, pnW2, idx - 24576, 128);
}

// ---------------------------------------------------------------------------
// CSR build
// ---------------------------------------------------------------------------
__global__ void hist_kernel(const int* __restrict__ eidx, int* __restrict__ counts) {
    int e = blockIdx.x * 256 + threadIdx.x;
    if (e < N_EDGES) {
        int r = eidx[N_EDGES + e];
        r = (r < 0) ? 0 : (r >= N_NODES ? N_NODES - 1 : r);
        atomicAdd(&counts[r], 1);
    }
}

__global__ __launch_bounds__(1024) void scan_kernel(const int* __restrict__ counts,
                                                    int* __restrict__ offsets,
                                                    int* __restrict__ cursor) {
    __shared__ int part[1024];
    const int t = threadIdx.x;
    const int CH = (N_NODES + 1023) / 1024;   // 49
    const int base = t * CH;
    int s = 0;
#pragma unroll 1
    for (int i = 0; i < CH; ++i) {
        int idx = base + i;
        if (idx < N_NODES) s += counts[idx];
    }
    part[t] = s;
    __syncthreads();
    for (int d = 1; d < 1024; d <<= 1) {
        int x = (t >= d) ? part[t - d] : 0;
        __syncthreads();
        part[t] += x;
        __syncthreads();
    }
    int run = part[t] - s;
#pragma unroll 1
    for (int i = 0; i < CH; ++i) {
        int idx = base + i;
        if (idx < N_NODES) {
            offsets[idx] = run;
            cursor[idx]  = run;
            run += counts[idx];
        }
    }
    if (t == 1023) offsets[N_NODES] = run;
}

__global__ void scatter_kernel(const int* __restrict__ eidx,
                               int* __restrict__ cursor, int* __restrict__ eids) {
    int e = blockIdx.x * 256 + threadIdx.x;
    if (e < N_EDGES) {
        int r = eidx[N_EDGES + e];
        r = (r < 0) ? 0 : (r >= N_NODES ? N_NODES - 1 : r);
        int pos = atomicAdd(&cursor[r], 1);
        eids[pos] = e;
    }
}

// ---------------------------------------------------------------------------
// Fused MLP core: round-6 GEMM structure + vectorized stats/LN and
// fast-math SiLU (exp2 + rcp instead of expf + IEEE div).
// ---------------------------------------------------------------------------
template<int ASTRIDE, int T1>
__device__ inline void mlp_core(char* lds,
                                const bf16x8* __restrict__ pW1,
                                const bf16x8* __restrict__ pW2,
                                const float* __restrict__ b1,
                                const float* __restrict__ g1,
                                const float* __restrict__ be1,
                                f32x4 (&acc2)[2][2]) {
    const int tid = threadIdx.x;
    const int w = tid >> 6;
    const int lane = tid & 63;
    const int l16 = lane & 15;
    const int g = lane >> 4;
    float* stats = (float*)(lds + 32 * ASTRIDE);   // [32][8]: (sum,sq) x 4 waves

    // ---- GEMM1: [32,K1] x [K1,256], wave w owns cols [64w, 64w+64) ----
    f32x4 acc[2][4];
#pragma unroll
    for (int m = 0; m < 2; ++m)
#pragma unroll
        for (int n = 0; n < 4; ++n) acc[m][n] = (f32x4){0.f, 0.f, 0.f, 0.f};
#pragma unroll
    for (int t = 0; t < T1; ++t) {
        bf16x8 af[2];
#pragma unroll
        for (int m = 0; m < 2; ++m)
            af[m] = *(const bf16x8*)(lds + (m * 16 + l16) * ASTRIDE + t * 64 + g * 16);
        const bf16x8* bp = pW1 + ((t * 16 + 4 * w) << 6) + lane;
#pragma unroll
        for (int n = 0; n < 4; ++n) {
            bf16x8 bf = bp[n << 6];
#pragma unroll
            for (int m = 0; m < 2; ++m)
                acc[m][n] = mfma16x16x32(af[m], bf, acc[m][n]);
        }
    }

    // ---- bias + per-row stats (vectorized over r; packed-f32 eligible) ----
    float b1v[4];
#pragma unroll
    for (int n = 0; n < 4; ++n) b1v[n] = b1[64 * w + 16 * n + l16];
#pragma unroll
    for (int m = 0; m < 2; ++m) {
#pragma unroll
        for (int n = 0; n < 4; ++n) acc[m][n] += b1v[n];
        f32x4 s = (acc[m][0] + acc[m][1]) + (acc[m][2] + acc[m][3]);
        f32x4 q = acc[m][0] * acc[m][0];
        q = acc[m][1] * acc[m][1] + q;
        q = acc[m][2] * acc[m][2] + q;
        q = acc[m][3] * acc[m][3] + q;
#pragma unroll
        for (int st = 1; st <= 8; st <<= 1) {
#pragma unroll
            for (int r = 0; r < 4; ++r) {
                s[r] += __shfl_xor(s[r], st);
                q[r] += __shfl_xor(q[r], st);
            }
        }
        if (l16 == 0) {
#pragma unroll
            for (int r = 0; r < 4; ++r) {
                int row = m * 16 + g * 4 + r;
                *(f32x2*)(stats + row * 8 + w * 2) = (f32x2){s[r], q[r]};
            }
        }
    }
    __syncthreads();   // GEMM1 A-reads done everywhere; stats visible

    // ---- finish LN stats; apply LN + fast SiLU; write h' (over A region) ----
    f32x4 mu4[2], rs4[2];
#pragma unroll
    for (int m = 0; m < 2; ++m)
#pragma unroll
        for (int r = 0; r < 4; ++r) {
            int row = m * 16 + g * 4 + r;
            f32x4 a = *(const f32x4*)(stats + row * 8);
            f32x4 b = *(const f32x4*)(stats + row * 8 + 4);
            float S = (a[0] + a[2]) + (b[0] + b[2]);
            float Q = (a[1] + a[3]) + (b[1] + b[3]);
            float mm = S * (1.f / 256.f);
            float vv = fmaxf(Q * (1.f / 256.f) - mm * mm, 0.f);
            mu4[m][r] = mm;
            rs4[m][r] = __builtin_amdgcn_rsqf(vv + 1e-5f);
        }
    float g1v[4], bev[4];
#pragma unroll
    for (int n = 0; n < 4; ++n) {
        g1v[n] = g1[64 * w + 16 * n + l16];
        bev[n] = be1[64 * w + 16 * n + l16];
    }
#pragma unroll
    for (int m = 0; m < 2; ++m)
#pragma unroll
        for (int n = 0; n < 4; ++n) {
            f32x4 y = (acc[m][n] - mu4[m]) * rs4[m];
            y = y * g1v[n] + bev[n];
            int col = 64 * w + 16 * n + l16;
#pragma unroll
            for (int r = 0; r < 4; ++r) {
                float e = __builtin_amdgcn_exp2f(y[r] * -1.44269504f);
                float x = y[r] * __builtin_amdgcn_rcpf(1.f + e);   // SiLU
                int row = m * 16 + g * 4 + r;
                *(__bf16*)(lds + row * 528 + col * 2) = (__bf16)x;
            }
        }
    __syncthreads();   // h' complete

    // ---- GEMM2: [32,256] x [256,128], wave w owns cols [32w, 32w+32) ----
#pragma unroll
    for (int m = 0; m < 2; ++m)
#pragma unroll
        for (int n = 0; n < 2; ++n) acc2[m][n] = (f32x4){0.f, 0.f, 0.f, 0.f};
#pragma unroll
    for (int t = 0; t < 8; ++t) {
        bf16x8 af[2];
#pragma unroll
        for (int m = 0; m < 2; ++m)
            af[m] = *(const bf16x8*)(lds + (m * 16 + l16) * 528 + t * 64 + g * 16);
        const bf16x8* bp = pW2 + ((t * 8 + 2 * w) << 6) + lane;
#pragma unroll
        for (int n = 0; n < 2; ++n) {
            bf16x8 bf = bp[n << 6];
#pragma unroll
            for (int m = 0; m < 2; ++m)
                acc2[m][n] = mfma16x16x32(af[m], bf, acc2[m][n]);
        }
    }
}

// ---------------------------------------------------------------------------
// Edge kernel: 32 edges/block, 5 blocks/CU (proven best); bf16 node-table gathers
// ---------------------------------------------------------------------------
__global__ __launch_bounds__(256, 5) void edge_kernel(
    const __bf16* __restrict__ nbf, const float* __restrict__ ef,
    const int* __restrict__ eidx,
    const bf16x8* __restrict__ pW1, const bf16x8* __restrict__ pW2,
    const float* __restrict__ b1, const float* __restrict__ g1,
    const float* __restrict__ be1, const float* __restrict__ b2,
    float* __restrict__ out_edges) {
    __shared__ __align__(16) char lds[MR * 784 + MR * 32];   // 26112 B
    const int tid = threadIdx.x;
    const int eb = blockIdx.x * MR;

    {   // stage A = [nbf[snd] | nbf[rcv] | cvt(ef)]
        int row = tid >> 3, l8 = tid & 7;
        int e = eb + row;
        int snd = eidx[e], rcv = eidx[N_EDGES + e];
        snd = (snd < 0) ? 0 : (snd >= N_NODES ? N_NODES - 1 : snd);
        rcv = (rcv < 0) ? 0 : (rcv >= N_NODES ? N_NODES - 1 : rcv);
        const char* ps = (const char*)(nbf + (size_t)snd * DIM) + (l8 << 5);
        const char* pr = (const char*)(nbf + (size_t)rcv * DIM) + (l8 << 5);
        char* dst = lds + row * 784 + (l8 << 5);
        *(i32x4*)dst         = *(const i32x4*)ps;
        *(i32x4*)(dst + 16)  = *(const i32x4*)(ps + 16);
        *(i32x4*)(dst + 256) = *(const i32x4*)pr;
        *(i32x4*)(dst + 272) = *(const i32x4*)(pr + 16);
        const float* pe = ef + (size_t)e * DIM + (l8 << 4);
        f32x4 a0 = ((const f32x4*)pe)[0], a1 = ((const f32x4*)pe)[1];
        f32x4 a2 = ((const f32x4*)pe)[2], a3 = ((const f32x4*)pe)[3];
        *(bf16x8*)(dst + 512) = cvt2_bf16(a0, a1);
        *(bf16x8*)(dst + 528) = cvt2_bf16(a2, a3);
    }
    __syncthreads();

    f32x4 acc2[2][2];
    mlp_core<784, 12>(lds, pW1, pW2, b1, g1, be1, acc2);

    {   // epilogue: out = ef + (h' @ W2 + b2), direct from registers
        const int w = tid >> 6, lane = tid & 63;
        const int l16 = lane & 15, g = lane >> 4;
        float b2v[2];
#pragma unroll
        for (int n = 0; n < 2; ++n) b2v[n] = b2[32 * w + 16 * n + l16];
#pragma unroll
        for (int m = 0; m < 2; ++m)
#pragma unroll
            for (int n = 0; n < 2; ++n)
#pragma unroll
                for (int r = 0; r < 4; ++r) {
                    int e = eb + m * 16 + g * 4 + r;
                    int col = 32 * w + 16 * n + l16;
                    size_t off = (size_t)e * DIM + col;
                    out_edges[off] = acc2[m][n][r] + b2v[n] + ef[off];
                }
    }
}

// ---------------------------------------------------------------------------
// Node kernel: 32 nodes/block; bf16 node staging; CSR gather unrolled x2
// ---------------------------------------------------------------------------
__global__ __launch_bounds__(256, 5) void node_kernel(
    const float* __restrict__ node, const __bf16* __restrict__ nbf,
    const float* __restrict__ out_edges,
    const int* __restrict__ offsets, const int* __restrict__ eids,
    const bf16x8* __restrict__ pW1, const bf16x8* __restrict__ pW2,
    const float* __restrict__ b1, const float* __restrict__ g1,
    const float* __restrict__ be1, const float* __restrict__ b2,
    float* __restrict__ out_nodes) {
    __shared__ __align__(16) char lds[MR * 528 + MR * 32];   // 17920 B
    const int tid = threadIdx.x;
    const int nb = blockIdx.x * MR;

    {   // stage node_input = [nbf[n] | csr aggregate] -> bf16
        int row = tid >> 3, l8 = tid & 7;
        int n = nb + row;
        int nc = (n > N_NODES - 1) ? N_NODES - 1 : n;
        const char* pn = (const char*)(nbf + (size_t)nc * DIM) + (l8 << 5);
        char* dst = lds + row * 528 + (l8 << 5);
        *(i32x4*)dst        = *(const i32x4*)pn;
        *(i32x4*)(dst + 16) = *(const i32x4*)(pn + 16);
        // aggregate: lane owns 16 contiguous cols [l8*16, +16)
        float a[16];
#pragma unroll
        for (int j = 0; j < 16; ++j) a[j] = 0.f;
        int st = offsets[nc], en = offsets[nc + 1];
        int i = st;
#pragma unroll 1
        for (; i + 2 <= en; i += 2) {
            int e0 = eids[i], e1 = eids[i + 1];
            const float* er0 = out_edges + (size_t)e0 * DIM + (l8 << 4);
            const float* er1 = out_edges + (size_t)e1 * DIM + (l8 << 4);
            f32x4 u0 = ((const f32x4*)er0)[0], u1 = ((const f32x4*)er0)[1];
            f32x4 u2 = ((const f32x4*)er0)[2], u3 = ((const f32x4*)er0)[3];
            f32x4 v0 = ((const f32x4*)er1)[0], v1 = ((const f32x4*)er1)[1];
            f32x4 v2 = ((const f32x4*)er1)[2], v3 = ((const f32x4*)er1)[3];
#pragma unroll
            for (int k = 0; k < 4; ++k) {
                a[0 + k]  += u0[k] + v0[k];
                a[4 + k]  += u1[k] + v1[k];
                a[8 + k]  += u2[k] + v2[k];
                a[12 + k] += u3[k] + v3[k];
            }
        }
        if (i < en) {
            int e0 = eids[i];
            const float* er0 = out_edges + (size_t)e0 * DIM + (l8 << 4);
#pragma unroll
            for (int k = 0; k < 4; ++k) {
                f32x4 v = ((const f32x4*)er0)[k];
                a[k * 4 + 0] += v[0]; a[k * 4 + 1] += v[1];
                a[k * 4 + 2] += v[2]; a[k * 4 + 3] += v[3];
            }
        }
        bf16x8 o0, o1;
#pragma unroll
        for (int j = 0; j < 8; ++j) { o0[j] = (__bf16)a[j]; o1[j] = (__bf16)a[8 + j]; }
        int cbase = 16 + (l8 << 1);
        *(bf16x8*)(lds + row * 528 + (cbase << 4)) = o0;
        *(bf16x8*)(lds + row * 528 + ((cbase + 1) << 4)) = o1;
    }
    __syncthreads();

    f32x4 acc2[2][2];
    mlp_core<528, 8>(lds, pW1, pW2, b1, g1, be1, acc2);

    {   // epilogue: out = node + (h' @ W2 + b2), guarded
        const int w = tid >> 6, lane = tid & 63;
        const int l16 = lane & 15, g = lane >> 4;
        float b2v[2];
#pragma unroll
        for (int n = 0; n < 2; ++n) b2v[n] = b2[32 * w + 16 * n + l16];
#pragma unroll
        for (int m = 0; m < 2; ++m)
#pragma unroll
            for (int n = 0; n < 2; ++n)
#pragma unroll
                for (int r = 0; r < 4; ++r) {
                    int nd = nb + m * 16 + g * 4 + r;
                    if (nd < N_NODES) {
                        int col = 32 * w + 16 * n + l16;
                        size_t off = (size_t)nd * DIM + col;
                        out_nodes[off] = acc2[m][n][r] + b2v[n] + node[off];
                    }
                }
    }
}

// ---------------------------------------------------------------------------
extern "C" void kernel_launch(void* const* d_in, const int* in_sizes, int n_in,
                              void* d_out, int out_size, void* d_ws, size_t ws_size,
                              hipStream_t stream) {
    const float* node  = (const float*)d_in[0];
    const float* ef    = (const float*)d_in[1];
    const int*   eidx  = (const int*)d_in[2];
    const float* eW1   = (const float*)d_in[3];
    const float* eb1   = (const float*)d_in[4];
    const float* eg1   = (const float*)d_in[5];
    const float* ebt1  = (const float*)d_in[6];
    const float* eW2   = (const float*)d_in[7];
    const float* eb2   = (const float*)d_in[8];
    const float* nW1   = (const float*)d_in[9];
    const float* nb1   = (const float*)d_in[10];
    const float* ng1   = (const float*)d_in[11];
    const float* nbt1  = (const float*)d_in[12];
    const float* nW2   = (const float*)d_in[13];
    const float* nb2   = (const float*)d_in[14];

    char* ws = (char*)d_ws;
    int* counts  = (int*)ws;
    int* offsets = counts + 50016;
    int* cursor  = offsets + 50016;
    int* eids    = cursor + 50016;
    char* nbase = (char*)(eids + 600064);
    __bf16* nbf = (__bf16*)(((uintptr_t)nbase + 255) & ~(uintptr_t)255);   // 12.8 MB
    __bf16* peW1 = nbf + (size_t)N_NODES * DIM;
    __bf16* peW2 = peW1 + 384 * 256;
    __bf16* pnW1 = peW2 + 256 * 128;
    __bf16* pnW2 = pnW1 + 256 * 256;

    hipMemsetAsync(counts, 0, 50000 * sizeof(int), stream);
    nbf_kernel<<<(N_NODES * 16 + 255) / 256, 256, 0, stream>>>(node, nbf);
    pack_all_kernel<<<112, 256, 0, stream>>>(eW1, eW2, nW1, nW2, peW1, peW2, pnW1, pnW2);

    hist_kernel<<<(N_EDGES + 255) / 256, 256, 0, stream>>>(eidx, counts);
    scan_kernel<<<1, 1024, 0, stream>>>(counts, offsets, cursor);
    scatter_kernel<<<(N_EDGES + 255) / 256, 256, 0, stream>>>(eidx, cursor, eids);

    float* out_nodes = (float*)d_out;
    float* out_edges = out_nodes + (size_t)N_NODES * DIM;

    edge_kernel<<<N_EDGES / MR, 256, 0, stream>>>(
        nbf, ef, eidx, (const bf16x8*)peW1, (const bf16x8*)peW2,
        eb1, eg1, ebt1, eb2, out_edges);
    node_kernel<<<(N_NODES + MR - 1) / MR, 256, 0, stream>>>(
        node, nbf, out_edges, offsets, eids, (const bf16x8*)pnW1, (const bf16x8*)pnW2,
        nb1, ng1, nbt1, nb2, out_nodes);
}